// Round 3
// baseline (321.996 us; speedup 1.0000x reference)
//
#include <hip/hip_runtime.h>

// Problem constants
#define BB 4
#define SS 4096
#define DIN 1024      // K for both GEMMs
#define DH 1024       // combined fast+slow channels
#define PN 2048       // GEMM1 logical output cols (z -> Zarr, h~ -> Harr)
#define MM (BB*SS)    // 16384 rows
#define NC 64         // scan chunks
#define CL 64         // chunk length (NC*CL == SS)

typedef unsigned short ushort_t;
typedef __attribute__((ext_vector_type(8))) short bf16x8;
typedef __attribute__((ext_vector_type(4))) float f32x4;
typedef __attribute__((ext_vector_type(4))) unsigned short u16x4;

__device__ inline float bf2f(ushort_t u) {
    union { float f; unsigned int i; } v; v.i = ((unsigned int)u) << 16; return v.f;
}
__device__ inline ushort_t f2bf(float f) {
    union { float f; unsigned int i; } v; v.f = f;
    unsigned int r = v.i + 0x7fffu + ((v.i >> 16) & 1u);  // round-to-nearest-even
    return (ushort_t)(r >> 16);
}
__device__ inline float sigmoidf_(float x) { return 1.0f / (1.0f + __expf(-x)); }

__device__ inline void load_lds16(const void* g, void* l) {
    __builtin_amdgcn_global_load_lds(
        (const __attribute__((address_space(1))) void*)g,
        (__attribute__((address_space(3))) void*)l, 16, 0, 0);
}

// Inline-asm LDS read: opaque to the compiler's alias/waitcnt machinery (r1
// lesson: plain C++ reads of As/Bs force compiler vmcnt(0) drains). WE enforce
// completion via explicit lgkmcnt + sched_barrier (rule #18).
__device__ __forceinline__ bf16x8 ds128(const ushort_t* p) {
    bf16x8 r;
    asm volatile("ds_read_b128 %0, %1"
                 : "=v"(r)
                 : "v"((const __attribute__((address_space(3))) ushort_t*)p));
    return r;
}

// ---------------------------------------------------------------------------
// Fallback (ws too small telemetry): write fp32 zeros to out.
__global__ void zero_out_kernel(float* out, int n) {
    int i = blockIdx.x * 256 + threadIdx.x;
    if (i < n) out[i] = 0.0f;
}

// ---------------------------------------------------------------------------
// Fused prep kernel, region-switched on blockIdx.x:
//  [0,512):        transpose 4x (1024x512 fp32 -> bf16 NxK) into WcatT
//  [512,768):      transpose Wg (1024x1024) into WgT
//  [768,17152):    cvt x fp32 -> bf16 (Xb)
//  [17152,17160):  bias concat (fp32)
#define PREP_NBLK 17160
__global__ __launch_bounds__(256) void prep_kernel(
    const float* __restrict__ x,
    const float* __restrict__ Wzf, const float* __restrict__ Wzs,
    const float* __restrict__ Whf, const float* __restrict__ Whs,
    const float* __restrict__ Wg,
    const float* __restrict__ bzf, const float* __restrict__ bzs,
    const float* __restrict__ bhf, const float* __restrict__ bhs,
    ushort_t* __restrict__ WcatT, ushort_t* __restrict__ WgT,
    ushort_t* __restrict__ Xb, float* __restrict__ bcat)
{
    __shared__ ushort_t tile[64][65];
    const int bx = blockIdx.x, tid = threadIdx.x;

    if (bx < 768) {
        // transpose region: dst[n][k] = bf16(src[k][n])
        const float* src; ushort_t* dst; int srcN, t;
        if (bx < 512) {
            int wi = bx >> 7; t = bx & 127; srcN = 512;
            const float* S[4] = {Wzf, Wzs, Whf, Whs};
            src = S[wi];
            dst = WcatT + (size_t)(wi * 512) * DIN;
        } else {
            t = bx - 512; srcN = 1024; src = Wg; dst = WgT;
        }
        const int k0 = (t & 15) * 64, n0 = (t >> 4) * 64;
        const int tx = tid & 63, ty = tid >> 6;
        #pragma unroll
        for (int i = ty; i < 64; i += 4)
            tile[i][tx] = f2bf(src[(size_t)(k0 + i) * srcN + n0 + tx]);
        __syncthreads();
        #pragma unroll
        for (int i = ty; i < 64; i += 4)
            dst[(size_t)(n0 + i) * DIN + k0 + tx] = tile[tx][i];
    } else if (bx < 17152) {
        // cvt x region: block handles 1024 elements
        size_t i = ((size_t)(bx - 768) * 256 + tid) * 4;
        float4 v = *(const float4*)(x + i);
        u16x4 o;
        o.x = f2bf(v.x); o.y = f2bf(v.y); o.z = f2bf(v.z); o.w = f2bf(v.w);
        *(u16x4*)(Xb + i) = o;
    } else {
        int i = (bx - 17152) * 256 + tid;  // 0..2047
        float v = (i < 512) ? bzf[i] : (i < 1024) ? bzs[i - 512]
                : (i < 1536) ? bhf[i - 1024] : bhs[i - 1536];
        bcat[i] = v;
    }
}

// ---------------------------------------------------------------------------
// GEMM: C(M x N) = A(M x K, bf16 rm, row stride lda) * Bt(N x K, bf16 rm)^T
//
// 256x256 tile, BK=64, 512 threads = 8 waves (2M x 4N). 8-phase pipeline,
// gray-code quadrants (00)(01)(11)(10) per buffer half; 24 b128/wave/K-tile.
//
// r3 schedule (fix of r2's zero-slack stalls):
//  * stages only at EVEN phases (4 gloads/wave each):
//      P2: buf0.{A0,B0}<-kt+2   P4: buf0.{B1,A1}<-kt+2
//      P6: buf1.{A0,B0}<-kt+3   P8: buf1.{B1,A1}<-kt+3
//  * vmcnt(8) at P4 and P8 tails: at P4 outstanding = {prevP6,prevP8,P2,P4}
//    (16) -> lands prevP6+prevP8; at P8 lands P2+P4.  Every LDS consume edge
//    is covered by a per-wave vmcnt + barrier STRICTLY BEFORE the read phase:
//      A0 (staged P2, read next-P1):  P8 lands P2          < next-P1  OK
//      B0 (staged P2, read next-P1):  P8 lands P2          < next-P1  OK
//      B1 (staged P4, read next-P1 post): P8 lands P4      < next-P1  OK
//      A1 (staged P4, read next-P3):  P8 lands P4          < next-P3  OK
//      buf1 regions (staged P6/P8, read P5/P7 next iter): P4 lands them  OK
//    -> staged data is 4-6 phases old at consume; vmcnt(8) never stalls.
//  * B-slack: bqB loads issue POST-MFMA at P1/P5, consumed P2/P6 (lgkm(0));
//    bqA+af issue pre-MFMA at P1/P5 (12 reads), af-only at P3/P7 (8 reads).
//  * staggered lgkm inside MFMA cluster: read order bqA(4) then af(8);
//    lgkmcnt(6/4/2/0) between mt-groups so mt0's MFMAs start once its own
//    6 reads land, hiding the rest under the matrix pipe.
//  * per-acc K order unchanged (kt ascending, kh 0,1) -> numerics identical.
// LDS XOR swizzle both-sides (0 bank conflicts measured r0-r2).
//
// EPI=0 (N=2048): col<1024 -> Zarr = bf16(sigmoid(acc+bias)), else Harr
// EPI=1 (N=1024): Out = sigmoid(acc + bg[col]) * bf2f(Hbf[row*DH+col])
#define BARR __builtin_amdgcn_s_barrier()
#define LGKM(n) { asm volatile("s_waitcnt lgkmcnt(" #n ")"); __builtin_amdgcn_sched_barrier(0); }
#define VM8   { asm volatile("s_waitcnt vmcnt(8)");   __builtin_amdgcn_sched_barrier(0); }

#define STG_A(b, h, kt) { \
    _Pragma("unroll") \
    for (int j = 0; j < 2; j++) { \
        int c = wave * 2 + j; \
        load_lds16(Ablk + (size_t)((h) * 128 + c * 8) * lda + (kt) * 64 + laneAOff, \
                   &As[(b) * 16384 + (h) * 8192 + c * 512]); \
    } }

#define STG_B(b, h, kt) { \
    _Pragma("unroll") \
    for (int j = 0; j < 2; j++) { \
        int c = wave * 2 + j; \
        load_lds16(Bblk + (size_t)((h) * 128 + c * 8) * K + (kt) * 64 + laneBOff, \
                   &Bs[(b) * 16384 + (h) * 8192 + c * 512]); \
    } }

// 8 asm reads: A fragments for half qm of buffer b (held across 2 phases)
#define LOADA(b, qm) { \
    const ushort_t* p0 = &As[(b) * 16384 + (qm) * 8192 + arow0 + acol0]; \
    const ushort_t* p1 = &As[(b) * 16384 + (qm) * 8192 + arow0 + acol1]; \
    _Pragma("unroll") \
    for (int mt = 0; mt < 4; mt++) { \
        af[mt][0] = ds128(p0 + mt * 1024); \
        af[mt][1] = ds128(p1 + mt * 1024); \
    } }

// 4 asm reads: B fragments for col-half qn of buffer b into bq (held)
#define LOADB(b, qn, bq) { \
    const ushort_t* p0 = &Bs[(b) * 16384 + (qn) * 8192 + brow0 + acol0]; \
    const ushort_t* p1 = &Bs[(b) * 16384 + (qn) * 8192 + brow0 + acol1]; \
    _Pragma("unroll") \
    for (int nt = 0; nt < 2; nt++) { \
        bq[nt][0] = ds128(p0 + nt * 1024); \
        bq[nt][1] = ds128(p1 + nt * 1024); \
    } }

// one mt-group: 4 MFMAs (2 nt x 2 kh), per-acc K order kh0,kh1 (unchanged)
#define MTG(qm, qn, bq, mt) { \
    acc[qm][qn][mt][0] = __builtin_amdgcn_mfma_f32_16x16x32_bf16( \
        af[mt][0], bq[0][0], acc[qm][qn][mt][0], 0, 0, 0); \
    acc[qm][qn][mt][0] = __builtin_amdgcn_mfma_f32_16x16x32_bf16( \
        af[mt][1], bq[0][1], acc[qm][qn][mt][0], 0, 0, 0); \
    acc[qm][qn][mt][1] = __builtin_amdgcn_mfma_f32_16x16x32_bf16( \
        af[mt][0], bq[1][0], acc[qm][qn][mt][1], 0, 0, 0); \
    acc[qm][qn][mt][1] = __builtin_amdgcn_mfma_f32_16x16x32_bf16( \
        af[mt][1], bq[1][1], acc[qm][qn][mt][1], 0, 0, 0); }

// staggered cluster: same-phase reads (bqA first, then af) gate mt-groups
#define MFMA16W(qm, qn, bq) { \
    __builtin_amdgcn_s_setprio(1); \
    LGKM(6); MTG(qm, qn, bq, 0); \
    LGKM(4); MTG(qm, qn, bq, 1); \
    LGKM(2); MTG(qm, qn, bq, 2); \
    LGKM(0); MTG(qm, qn, bq, 3); \
    __builtin_amdgcn_s_setprio(0); }

// no-wait cluster: all operands already in regs / landed
#define MFMA16N(qm, qn, bq) { \
    __builtin_amdgcn_s_setprio(1); \
    MTG(qm, qn, bq, 0); MTG(qm, qn, bq, 1); \
    MTG(qm, qn, bq, 2); MTG(qm, qn, bq, 3); \
    __builtin_amdgcn_s_setprio(0); }

template <int EPI, int NB>
__global__ __launch_bounds__(512, 2) void gemm_kernel(
    const ushort_t* __restrict__ A, const ushort_t* __restrict__ Bt,
    int K, int lda,
    const float* __restrict__ bias,
    ushort_t* __restrict__ Zarr, ushort_t* __restrict__ Harr,
    const float* __restrict__ bg, const ushort_t* __restrict__ Hbf,
    float* __restrict__ Out)
{
    __shared__ alignas(16) ushort_t As[2 * 256 * 64];   // 64 KiB
    __shared__ alignas(16) ushort_t Bs[2 * 256 * 64];   // 64 KiB

    const int tid  = threadIdx.x;
    const int lane = tid & 63;
    const int wave = tid >> 6;       // 0..7
    const int wm   = wave & 1;       // M granule (64 rows within a 128-half)
    const int wn   = wave >> 1;      // 0..3, N granule (32 cols within a 128-half)
    const int lrow = lane & 15;
    const int kgrp = lane >> 4;

    // XCD-aware work mapping (nwg % 8 == 0 for both GEMMs)
    const int id  = blockIdx.x;
    const int xcd = id & 7;
    const int s   = id >> 3;
    const int mBase = (xcd + 8 * (s / NB)) * 256;
    const int nBase = (s % NB) * 256;

    f32x4 acc[2][2][4][2] = {};      // [qm][qn][mt][nt] -> 128 regs (AGPR)

    const ushort_t* Ablk = A  + (size_t)mBase * lda;
    const ushort_t* Bblk = Bt + (size_t)nBase * K;
    // pre-swizzled per-lane source offset: row = lane/8, col group = (lane%8)^(lane/8)
    const int laneAOff = (lane >> 3) * lda + (((lane & 7) ^ (lane >> 3)) * 8);
    const int laneBOff = (lane >> 3) * K   + (((lane & 7) ^ (lane >> 3)) * 8);

    // per-thread fragment read offsets (ushort units); read row r has r&7 == lrow&7
    const int arow0 = (wm * 64 + lrow) * 64;
    const int brow0 = (wn * 32 + lrow) * 64;
    const int acol0 = ((kgrp    ) ^ (lrow & 7)) * 8;   // kh = 0
    const int acol1 = ((4 + kgrp) ^ (lrow & 7)) * 8;   // kh = 1

    const int NKT = K >> 6;          // 16 K-tiles
    const int NIT = NKT >> 1;        // 8 iterations (2 K-tiles each)

    bf16x8 af[4][2], bqA[2][2], bqB[2][2];   // held operand fragments (64 regs)

    // Prologue: buf0 <- tile0 (4 regions, 8 loads), buf1 <- tile1 (8 loads).
    // vmcnt(8) lands all of buf0; buf1 lands via first P4's vmcnt(8).
    STG_A(0, 0, 0); STG_B(0, 0, 0); STG_B(0, 1, 0); STG_A(0, 1, 0);
    STG_A(1, 0, 1); STG_B(1, 0, 1); STG_B(1, 1, 1); STG_A(1, 1, 1);
    VM8;
    BARR;

    for (int i = 0; i < NIT; i++) {
        const int ktn0 = (2 * i + 2) & (NKT - 1);   // wraps harmlessly on last iter
        const int ktn1 = (2 * i + 3) & (NKT - 1);

        // ---- buf0 (K-tile 2i), quadrant order (00)(01)(11)(10) ----
        // P1: pre 12 reads (bqA then af), post 4 (bqB, slack -> P2)
        LOADB(0, 0, bqA); LOADA(0, 0);
        BARR;
        MFMA16W(0, 0, bqA);
        LOADB(0, 1, bqB);
        BARR;
        // P2: stage buf0.{A0,B0}; bqB landed check only
        STG_A(0, 0, ktn0); STG_B(0, 0, ktn0);
        BARR;
        LGKM(0); MFMA16N(0, 1, bqB);
        BARR;
        // P3: af(m1) same-phase (staggered)
        LOADA(0, 1);
        BARR;
        MFMA16W(1, 1, bqB);
        BARR;
        // P4: stage buf0.{B1,A1}; pure-reg MFMA; vmcnt(8) lands prevP6+prevP8
        STG_B(0, 1, ktn0); STG_A(0, 1, ktn0);
        BARR;
        MFMA16N(1, 0, bqA);
        VM8;
        BARR;

        // ---- buf1 (K-tile 2i+1) ----
        // P5
        LOADB(1, 0, bqA); LOADA(1, 0);
        BARR;
        MFMA16W(0, 0, bqA);
        LOADB(1, 1, bqB);
        BARR;
        // P6
        STG_A(1, 0, ktn1); STG_B(1, 0, ktn1);
        BARR;
        LGKM(0); MFMA16N(0, 1, bqB);
        BARR;
        // P7
        LOADA(1, 1);
        BARR;
        MFMA16W(1, 1, bqB);
        BARR;
        // P8: vmcnt(8) lands P2+P4 -> covers next iter's P1/P3 reads
        STG_B(1, 1, ktn1); STG_A(1, 1, ktn1);
        BARR;
        MFMA16N(1, 0, bqA);
        VM8;
        BARR;
    }
    LGKM(0);   // drain any DS op before epilogue register reuse

    // Epilogue. C/D layout: col = lane&15, row = (lane>>4)*4 + reg  [m89/m91]
    const int rquad = (lane >> 4) * 4;

    if (EPI == 0) {
        const bool isz = (nBase < DH);
        ushort_t* Dst  = isz ? Zarr : Harr;
        const int csub = isz ? 0 : DH;
        #pragma unroll
        for (int qm = 0; qm < 2; qm++)
        #pragma unroll
        for (int qn = 0; qn < 2; qn++)
        #pragma unroll
        for (int nt = 0; nt < 2; nt++) {
            int col  = nBase + qn * 128 + wn * 32 + nt * 16 + lrow;
            float bv = bias[col];
            int dcol = col - csub;
            #pragma unroll
            for (int mt = 0; mt < 4; mt++) {
                int row = mBase + qm * 128 + wm * 64 + mt * 16 + rquad;
                ushort_t* p = Dst + (size_t)row * DH + dcol;
                #pragma unroll
                for (int r = 0; r < 4; r++) {
                    float v = acc[qm][qn][mt][nt][r] + bv;
                    if (isz) v = sigmoidf_(v);
                    p[(size_t)r * DH] = f2bf(v);
                }
            }
        }
    } else {
        #pragma unroll
        for (int qm = 0; qm < 2; qm++)
        #pragma unroll
        for (int qn = 0; qn < 2; qn++)
        #pragma unroll
        for (int nt = 0; nt < 2; nt++) {
            int col  = nBase + qn * 128 + wn * 32 + nt * 16 + lrow;
            float bv = bg[col];
            #pragma unroll
            for (int mt = 0; mt < 4; mt++) {
                int row = mBase + qm * 128 + wm * 64 + mt * 16 + rquad;
                #pragma unroll
                for (int r = 0; r < 4; r++) {
                    float g = sigmoidf_(acc[qm][qn][mt][nt][r] + bv);
                    float h = bf2f(Hbf[(size_t)(row + r) * DH + col]);
                    Out[(size_t)(row + r) * DH + col] = g * h;
                }
            }
        }
    }
}

// ---------------------------------------------------------------------------
// Scan pass 1: per-chunk aggregates, 4 channels/thread (u16x4 = 8B loads),
// 4 independent recurrence chains per thread for ILP. Block covers all 1024
// channels. grid (NC, BB), block 256.
__global__ __launch_bounds__(256) void scan_chunk_agg(
    const ushort_t* __restrict__ Zarr, const ushort_t* __restrict__ Harr,
    float* __restrict__ Agg, float* __restrict__ Bagg)
{
    const int c4    = threadIdx.x * 4;   // channel base 0..1020
    const int chunk = blockIdx.x;
    const int b     = blockIdx.y;
    const size_t s0 = ((size_t)b * SS + (size_t)chunk * CL) * DH + c4;
    const ushort_t* Zp = Zarr + s0;
    const ushort_t* Hp = Harr + s0;

    float A0 = 1.0f, A1 = 1.0f, A2 = 1.0f, A3 = 1.0f;
    float B0 = 0.0f, B1 = 0.0f, B2 = 0.0f, B3 = 0.0f;
    #pragma unroll 8
    for (int t = 0; t < CL; t++) {
        u16x4 zv = *(const u16x4*)(Zp + (size_t)t * DH);
        u16x4 hv = *(const u16x4*)(Hp + (size_t)t * DH);
        float z0 = bf2f(zv.x), z1 = bf2f(zv.y), z2 = bf2f(zv.z), z3 = bf2f(zv.w);
        float h0 = bf2f(hv.x), h1 = bf2f(hv.y), h2 = bf2f(hv.z), h3 = bf2f(hv.w);
        A0 *= 1.0f - z0;  B0 = (1.0f - z0) * B0 + z0 * h0;
        A1 *= 1.0f - z1;  B1 = (1.0f - z1) * B1 + z1 * h1;
        A2 *= 1.0f - z2;  B2 = (1.0f - z2) * B2 + z2 * h2;
        A3 *= 1.0f - z3;  B3 = (1.0f - z3) * B3 + z3 * h3;
    }
    const size_t idx = ((size_t)(b * NC + chunk)) * DH + c4;
    *(float4*)(Agg  + idx) = make_float4(A0, A1, A2, A3);
    *(float4*)(Bagg + idx) = make_float4(B0, B1, B2, B3);
}

// Scan pass 2: carry across chunks. 4096 threads, 64 sequential L2-hot steps.
__global__ void scan_carry(const float* __restrict__ Agg, const float* __restrict__ Bagg,
                           float* __restrict__ Hinit)
{
    const int i = blockIdx.x * 256 + threadIdx.x;  // 0..4095
    const int b = i >> 10, c = i & 1023;
    float h = 0.0f;
    for (int j = 0; j < NC; j++) {
        const size_t idx = ((size_t)(b * NC + j)) * DH + c;
        Hinit[idx] = h;
        h = Agg[idx] * h + Bagg[idx];
    }
}

// Scan pass 3: re-apply with chunk-initial h (4 ch/thread, vector I/O);
// write h (bf16) in place over Harr.
__global__ __launch_bounds__(256) void scan_apply(
    const ushort_t* __restrict__ Zarr, ushort_t* Harr, const float* __restrict__ Hinit)
{
    const int c4    = threadIdx.x * 4;
    const int chunk = blockIdx.x;
    const int b     = blockIdx.y;
    const size_t s0 = ((size_t)b * SS + (size_t)chunk * CL) * DH + c4;
    const ushort_t* Zp = Zarr + s0;
    ushort_t*       Hp = Harr + s0;

    float4 hi = *(const float4*)(Hinit + ((size_t)(b * NC + chunk)) * DH + c4);
    float h0 = hi.x, h1 = hi.y, h2 = hi.z, h3 = hi.w;
    #pragma unroll 8
    for (int t = 0; t < CL; t++) {
        u16x4 zv = *(const u16x4*)(Zp + (size_t)t * DH);
        u16x4 hv = *(const u16x4*)(Hp + (size_t)t * DH);
        float z0 = bf2f(zv.x), z1 = bf2f(zv.y), z2 = bf2f(zv.z), z3 = bf2f(zv.w);
        float t0 = bf2f(hv.x), t1 = bf2f(hv.y), t2 = bf2f(hv.z), t3 = bf2f(hv.w);
        h0 = (1.0f - z0) * h0 + z0 * t0;
        h1 = (1.0f - z1) * h1 + z1 * t1;
        h2 = (1.0f - z2) * h2 + z2 * t2;
        h3 = (1.0f - z3) * h3 + z3 * t3;
        u16x4 o;
        o.x = f2bf(h0); o.y = f2bf(h1); o.z = f2bf(h2); o.w = f2bf(h3);
        *(u16x4*)(Hp + (size_t)t * DH) = o;
    }
}

// ---------------------------------------------------------------------------
extern "C" void kernel_launch(void* const* d_in, const int* in_sizes, int n_in,
                              void* d_out, int out_size, void* d_ws, size_t ws_size,
                              hipStream_t stream)
{
    const float* x   = (const float*)d_in[0];
    const float* Wzf = (const float*)d_in[1];
    const float* bzf = (const float*)d_in[2];
    const float* Whf = (const float*)d_in[3];
    const float* bhf = (const float*)d_in[4];
    const float* Wzs = (const float*)d_in[5];
    const float* bzs = (const float*)d_in[6];
    const float* Whs = (const float*)d_in[7];
    const float* bhs = (const float*)d_in[8];
    const float* Wg  = (const float*)d_in[9];
    const float* bg  = (const float*)d_in[10];

    const size_t NEED = (size_t)42 << 20;
    if (ws_size < NEED) {
        zero_out_kernel<<<(MM * DH + 255) / 256, 256, 0, stream>>>((float*)d_out, MM * DH);
        return;
    }

    // Workspace layout (42 MiB):
    char* ws = (char*)d_ws;
    ushort_t* WcatT = (ushort_t*)(ws);                                    // 0..4 MiB
    ushort_t* WgT   = (ushort_t*)(ws + ((size_t)4 << 20));                // 4..6 MiB
    float*    bcat  = (float*)   (ws + ((size_t)6 << 20));                // 8 KiB
    float*    Agg   = (float*)   (ws + ((size_t)6 << 20) + (64 << 10));   // 1 MiB
    float*    Bagg  = (float*)   (ws + ((size_t)7 << 20) + (64 << 10));   // 1 MiB
    float*    Hinit = (float*)   (ws + ((size_t)8 << 20) + (64 << 10));   // 1 MiB
    ushort_t* Harr  = (ushort_t*)(ws + ((size_t)10 << 20));               // 10..42 MiB

    // d_out (64 MiB fp32) doubles as bf16 scratch until GEMM2 overwrites it:
    ushort_t* Xb   = (ushort_t*)d_out;              // [0..32 MiB): x in bf16
    ushort_t* Zarr = Xb + (size_t)MM * DH;          // [32..64 MiB): post-sigmoid z

    dim3 blk(256);

    // Fused prep: 5 transposes + x cvt + bias concat
    prep_kernel<<<PREP_NBLK, blk, 0, stream>>>(
        x, Wzf, Wzs, Whf, Whs, Wg, bzf, bzs, bhf, bhs, WcatT, WgT, Xb, bcat);

    // GEMM1: Zarr = sigmoid(Xb@Wz+bz), Harr = Xb@Wh+bh   (M=16384, N=2048, K=1024)
    // 256x256 tiles: grid 64x8 = 512 blocks, 512 threads.
    gemm_kernel<0, PN / 256><<<(MM / 256) * (PN / 256), dim3(512), 0, stream>>>(
        Xb, WcatT, DIN, /*lda=*/DIN, bcat, Zarr, Harr, nullptr, nullptr, nullptr);

    // Chunked scan, 3 deterministic passes (h in place over Harr)
    scan_chunk_agg<<<dim3(NC, BB), blk, 0, stream>>>(Zarr, Harr, Agg, Bagg);
    scan_carry<<<16, 256, 0, stream>>>(Agg, Bagg, Hinit);
    scan_apply<<<dim3(NC, BB), blk, 0, stream>>>(Zarr, Harr, Hinit);

    // GEMM2: out = sigmoid(H @ Wg + bg) * H   (fp32 out, overwrites all of d_out)
    // 256x256 tiles: grid 64x4 = 256 blocks.
    gemm_kernel<1, DH / 256><<<(MM / 256) * (DH / 256), dim3(512), 0, stream>>>(
        Harr, WgT, DIN, /*lda=*/DH, nullptr, nullptr, nullptr, bg, /*Hbf=*/Harr,
        (float*)d_out);
}

// Round 4
// 308.533 us; speedup vs baseline: 1.0436x; 1.0436x over previous
//
#include <hip/hip_runtime.h>

// Problem constants
#define BB 4
#define SS 4096
#define DIN 1024      // K for both GEMMs
#define DH 1024       // combined fast+slow channels
#define PN 2048       // GEMM1 logical output cols (z -> Zarr, h~ -> Harr)
#define MM (BB*SS)    // 16384 rows
#define NC 64         // scan chunks
#define CL 64         // chunk length (NC*CL == SS)

typedef unsigned short ushort_t;
typedef __attribute__((ext_vector_type(8))) short bf16x8;
typedef __attribute__((ext_vector_type(4))) float f32x4;
typedef __attribute__((ext_vector_type(4))) unsigned short u16x4;

__device__ inline float bf2f(ushort_t u) {
    union { float f; unsigned int i; } v; v.i = ((unsigned int)u) << 16; return v.f;
}
__device__ inline ushort_t f2bf(float f) {
    union { float f; unsigned int i; } v; v.f = f;
    unsigned int r = v.i + 0x7fffu + ((v.i >> 16) & 1u);  // round-to-nearest-even
    return (ushort_t)(r >> 16);
}
__device__ inline float sigmoidf_(float x) { return 1.0f / (1.0f + __expf(-x)); }

__device__ inline void load_lds16(const void* g, void* l) {
    __builtin_amdgcn_global_load_lds(
        (const __attribute__((address_space(1))) void*)g,
        (__attribute__((address_space(3))) void*)l, 16, 0, 0);
}

// Inline-asm LDS read: opaque to the compiler's alias/waitcnt machinery (r1
// lesson: plain C++ reads of As/Bs force compiler vmcnt(0) drains). WE enforce
// completion via explicit lgkmcnt + sched_barrier (rule #18).
__device__ __forceinline__ bf16x8 ds128(const ushort_t* p) {
    bf16x8 r;
    asm volatile("ds_read_b128 %0, %1"
                 : "=v"(r)
                 : "v"((const __attribute__((address_space(3))) ushort_t*)p));
    return r;
}

// ---------------------------------------------------------------------------
// Fallback (ws too small telemetry): write fp32 zeros to out.
__global__ void zero_out_kernel(float* out, int n) {
    int i = blockIdx.x * 256 + threadIdx.x;
    if (i < n) out[i] = 0.0f;
}

// ---------------------------------------------------------------------------
// Fused prep kernel, region-switched on blockIdx.x:
//  [0,512):        transpose 4x (1024x512 fp32 -> bf16 NxK) into WcatT
//  [512,768):      transpose Wg (1024x1024) into WgT
//  [768,17152):    cvt x fp32 -> bf16 (Xb)
//  [17152,17160):  bias concat (fp32)
#define PREP_NBLK 17160
__global__ __launch_bounds__(256) void prep_kernel(
    const float* __restrict__ x,
    const float* __restrict__ Wzf, const float* __restrict__ Wzs,
    const float* __restrict__ Whf, const float* __restrict__ Whs,
    const float* __restrict__ Wg,
    const float* __restrict__ bzf, const float* __restrict__ bzs,
    const float* __restrict__ bhf, const float* __restrict__ bhs,
    ushort_t* __restrict__ WcatT, ushort_t* __restrict__ WgT,
    ushort_t* __restrict__ Xb, float* __restrict__ bcat)
{
    __shared__ ushort_t tile[64][65];
    const int bx = blockIdx.x, tid = threadIdx.x;

    if (bx < 768) {
        // transpose region: dst[n][k] = bf16(src[k][n])
        const float* src; ushort_t* dst; int srcN, t;
        if (bx < 512) {
            int wi = bx >> 7; t = bx & 127; srcN = 512;
            const float* S[4] = {Wzf, Wzs, Whf, Whs};
            src = S[wi];
            dst = WcatT + (size_t)(wi * 512) * DIN;
        } else {
            t = bx - 512; srcN = 1024; src = Wg; dst = WgT;
        }
        const int k0 = (t & 15) * 64, n0 = (t >> 4) * 64;
        const int tx = tid & 63, ty = tid >> 6;
        #pragma unroll
        for (int i = ty; i < 64; i += 4)
            tile[i][tx] = f2bf(src[(size_t)(k0 + i) * srcN + n0 + tx]);
        __syncthreads();
        #pragma unroll
        for (int i = ty; i < 64; i += 4)
            dst[(size_t)(n0 + i) * DIN + k0 + tx] = tile[tx][i];
    } else if (bx < 17152) {
        // cvt x region: block handles 1024 elements
        size_t i = ((size_t)(bx - 768) * 256 + tid) * 4;
        float4 v = *(const float4*)(x + i);
        u16x4 o;
        o.x = f2bf(v.x); o.y = f2bf(v.y); o.z = f2bf(v.z); o.w = f2bf(v.w);
        *(u16x4*)(Xb + i) = o;
    } else {
        int i = (bx - 17152) * 256 + tid;  // 0..2047
        float v = (i < 512) ? bzf[i] : (i < 1024) ? bzs[i - 512]
                : (i < 1536) ? bhf[i - 1024] : bhs[i - 1536];
        bcat[i] = v;
    }
}

// ---------------------------------------------------------------------------
// GEMM: C(M x N) = A(M x K, bf16 rm, row stride lda) * Bt(N x K, bf16 rm)^T
//
// 256x256 tile, BK=64, 512 threads = 8 waves (2M x 4N). 8-phase pipeline,
// gray-code quadrants (00)(01)(11)(10) per buffer half; 24 b128/wave/K-tile.
// EXACTLY the r2 schedule (84 us measured) with ONE change (r4):
//
//   MFMA cluster order is kh-MAJOR: all 8 independent (mt x nt) MFMAs at
//   kh=0, then all 8 at kh=1. r2 ordered per-acc pairs back-to-back
//   (dependence distance 1 on the same accumulator -> in-order issue stalls
//   at full MFMA latency per pair). Distance is now 8; per-accumulator
//   K-order (kh0 then kh1) unchanged -> numerics identical.
//
// r2 schedule recap:
//  * Region read-sets per buffer half (4 phases): A0@P1,B0@P1, B1@P2, A1@P3.
//  * Stages (2 gloads each): P1:buf1.A1<-kt1  P2:buf1.B1<-kt1
//    P3:buf0.A0<-kt0+2  P4:buf0.B0<-kt0+2  P5:buf0.B1  P6:buf0.A1
//    P7:buf1.A0<-kt1+2  P8:buf1.B0<-kt1+2
//  * vmcnt(4) at P4/P8 tails only; all consume edges land >=1 phase early.
// LDS XOR swizzle both-sides (0 bank conflicts measured r0-r3).
//
// EPI=0 (N=2048): col<1024 -> Zarr = bf16(sigmoid(acc+bias)), else Harr
// EPI=1 (N=1024): Out = sigmoid(acc + bg[col]) * bf2f(Hbf[row*DH+col])
#define BARR __builtin_amdgcn_s_barrier()
#define WAITK { asm volatile("s_waitcnt lgkmcnt(0)"); __builtin_amdgcn_sched_barrier(0); }
#define VM4   { asm volatile("s_waitcnt vmcnt(4)");   __builtin_amdgcn_sched_barrier(0); }

#define STG_A(b, h, kt) { \
    _Pragma("unroll") \
    for (int j = 0; j < 2; j++) { \
        int c = wave * 2 + j; \
        load_lds16(Ablk + (size_t)((h) * 128 + c * 8) * lda + (kt) * 64 + laneAOff, \
                   &As[(b) * 16384 + (h) * 8192 + c * 512]); \
    } }

#define STG_B(b, h, kt) { \
    _Pragma("unroll") \
    for (int j = 0; j < 2; j++) { \
        int c = wave * 2 + j; \
        load_lds16(Bblk + (size_t)((h) * 128 + c * 8) * K + (kt) * 64 + laneBOff, \
                   &Bs[(b) * 16384 + (h) * 8192 + c * 512]); \
    } }

// 8 asm reads: A fragments for half qm of buffer b (held across 2 phases)
#define LOADA(b, qm) { \
    const ushort_t* p0 = &As[(b) * 16384 + (qm) * 8192 + arow0 + acol0]; \
    const ushort_t* p1 = &As[(b) * 16384 + (qm) * 8192 + arow0 + acol1]; \
    _Pragma("unroll") \
    for (int mt = 0; mt < 4; mt++) { \
        af[mt][0] = ds128(p0 + mt * 1024); \
        af[mt][1] = ds128(p1 + mt * 1024); \
    } }

// 4 asm reads: B fragments for col-half qn of buffer b into bq (held)
#define LOADB(b, qn, bq) { \
    const ushort_t* p0 = &Bs[(b) * 16384 + (qn) * 8192 + brow0 + acol0]; \
    const ushort_t* p1 = &Bs[(b) * 16384 + (qn) * 8192 + brow0 + acol1]; \
    _Pragma("unroll") \
    for (int nt = 0; nt < 2; nt++) { \
        bq[nt][0] = ds128(p0 + nt * 1024); \
        bq[nt][1] = ds128(p1 + nt * 1024); \
    } }

// 16 MFMAs, kh-major: 8 independent MFMAs per kh group; same-acc dependence
// distance = 8 (was 1 in r2). Per-acc K order still kh0 -> kh1.
#define MFMA16(qm, qn, bq) { \
    __builtin_amdgcn_s_setprio(1); \
    _Pragma("unroll") \
    for (int kh = 0; kh < 2; kh++) { \
        _Pragma("unroll") \
        for (int mt = 0; mt < 4; mt++) { \
            _Pragma("unroll") \
            for (int nt = 0; nt < 2; nt++) { \
                acc[qm][qn][mt][nt] = __builtin_amdgcn_mfma_f32_16x16x32_bf16( \
                    af[mt][kh], bq[nt][kh], acc[qm][qn][mt][nt], 0, 0, 0); \
            } } } \
    __builtin_amdgcn_s_setprio(0); }

template <int EPI, int NB>
__global__ __launch_bounds__(512, 2) void gemm_kernel(
    const ushort_t* __restrict__ A, const ushort_t* __restrict__ Bt,
    int K, int lda,
    const float* __restrict__ bias,
    ushort_t* __restrict__ Zarr, ushort_t* __restrict__ Harr,
    const float* __restrict__ bg, const ushort_t* __restrict__ Hbf,
    float* __restrict__ Out)
{
    __shared__ alignas(16) ushort_t As[2 * 256 * 64];   // 64 KiB
    __shared__ alignas(16) ushort_t Bs[2 * 256 * 64];   // 64 KiB

    const int tid  = threadIdx.x;
    const int lane = tid & 63;
    const int wave = tid >> 6;       // 0..7
    const int wm   = wave & 1;       // M granule (64 rows within a 128-half)
    const int wn   = wave >> 1;      // 0..3, N granule (32 cols within a 128-half)
    const int lrow = lane & 15;
    const int kgrp = lane >> 4;

    // XCD-aware work mapping (nwg % 8 == 0 for both GEMMs)
    const int id  = blockIdx.x;
    const int xcd = id & 7;
    const int s   = id >> 3;
    const int mBase = (xcd + 8 * (s / NB)) * 256;
    const int nBase = (s % NB) * 256;

    f32x4 acc[2][2][4][2] = {};      // [qm][qn][mt][nt] -> 128 regs (AGPR)

    const ushort_t* Ablk = A  + (size_t)mBase * lda;
    const ushort_t* Bblk = Bt + (size_t)nBase * K;
    // pre-swizzled per-lane source offset: row = lane/8, col group = (lane%8)^(lane/8)
    const int laneAOff = (lane >> 3) * lda + (((lane & 7) ^ (lane >> 3)) * 8);
    const int laneBOff = (lane >> 3) * K   + (((lane & 7) ^ (lane >> 3)) * 8);

    // per-thread fragment read offsets (ushort units); read row r has r&7 == lrow&7
    const int arow0 = (wm * 64 + lrow) * 64;
    const int brow0 = (wn * 32 + lrow) * 64;
    const int acol0 = ((kgrp    ) ^ (lrow & 7)) * 8;   // kh = 0
    const int acol1 = ((4 + kgrp) ^ (lrow & 7)) * 8;   // kh = 1

    const int NKT = K >> 6;          // 16 K-tiles
    const int NIT = NKT >> 1;        // 8 iterations (2 K-tiles each)

    bf16x8 af[4][2], bqA[2][2], bqB[2][2];   // held operand fragments (64 regs)

    // Prologue: buf0 <- tile0 (all 4 half-regions), buf1 <- tile1 (A0,B0).
    // vmcnt(4) leaves only buf1's 4 instrs outstanding -> buf0 fully landed.
    STG_A(0, 0, 0); STG_B(0, 0, 0); STG_A(0, 1, 0); STG_B(0, 1, 0);
    STG_A(1, 0, 1); STG_B(1, 0, 1);
    VM4;
    BARR;

    for (int i = 0; i < NIT; i++) {
        const int kt1  = 2 * i + 1;
        const int ktn0 = (2 * i + 2) & (NKT - 1);   // wraps harmlessly on last iter
        const int ktn1 = (2 * i + 3) & (NKT - 1);

        // ---- buf0 (K-tile kt0 = 2i), gray order (00)(01)(11)(10) ----
        // P1
        LOADA(0, 0); LOADB(0, 0, bqA); STG_A(1, 1, kt1);
        BARR; WAITK; MFMA16(0, 0, bqA); BARR;
        // P2
        LOADB(0, 1, bqB); STG_B(1, 1, kt1);
        BARR; WAITK; MFMA16(0, 1, bqB); BARR;
        // P3
        LOADA(0, 1); STG_A(0, 0, ktn0);
        BARR; WAITK; MFMA16(1, 1, bqB); BARR;
        // P4 (no LDS reads; af + bqA still valid in regs)
        STG_B(0, 0, ktn0);
        BARR; MFMA16(1, 0, bqA); VM4; BARR;

        // ---- buf1 (K-tile kt1 = 2i+1) ----
        // P5
        LOADA(1, 0); LOADB(1, 0, bqA); STG_B(0, 1, ktn0);
        BARR; WAITK; MFMA16(0, 0, bqA); BARR;
        // P6
        LOADB(1, 1, bqB); STG_A(0, 1, ktn0);
        BARR; WAITK; MFMA16(0, 1, bqB); BARR;
        // P7
        LOADA(1, 1); STG_A(1, 0, ktn1);
        BARR; WAITK; MFMA16(1, 1, bqB); BARR;
        // P8
        STG_B(1, 0, ktn1);
        BARR; MFMA16(1, 0, bqA); VM4; BARR;
    }
    WAITK;   // drain any DS op before epilogue register reuse

    // Epilogue. C/D layout: col = lane&15, row = (lane>>4)*4 + reg  [m89/m91]
    const int rquad = (lane >> 4) * 4;

    if (EPI == 0) {
        const bool isz = (nBase < DH);
        ushort_t* Dst  = isz ? Zarr : Harr;
        const int csub = isz ? 0 : DH;
        #pragma unroll
        for (int qm = 0; qm < 2; qm++)
        #pragma unroll
        for (int qn = 0; qn < 2; qn++)
        #pragma unroll
        for (int nt = 0; nt < 2; nt++) {
            int col  = nBase + qn * 128 + wn * 32 + nt * 16 + lrow;
            float bv = bias[col];
            int dcol = col - csub;
            #pragma unroll
            for (int mt = 0; mt < 4; mt++) {
                int row = mBase + qm * 128 + wm * 64 + mt * 16 + rquad;
                ushort_t* p = Dst + (size_t)row * DH + dcol;
                #pragma unroll
                for (int r = 0; r < 4; r++) {
                    float v = acc[qm][qn][mt][nt][r] + bv;
                    if (isz) v = sigmoidf_(v);
                    p[(size_t)r * DH] = f2bf(v);
                }
            }
        }
    } else {
        #pragma unroll
        for (int qm = 0; qm < 2; qm++)
        #pragma unroll
        for (int qn = 0; qn < 2; qn++)
        #pragma unroll
        for (int nt = 0; nt < 2; nt++) {
            int col  = nBase + qn * 128 + wn * 32 + nt * 16 + lrow;
            float bv = bg[col];
            #pragma unroll
            for (int mt = 0; mt < 4; mt++) {
                int row = mBase + qm * 128 + wm * 64 + mt * 16 + rquad;
                #pragma unroll
                for (int r = 0; r < 4; r++) {
                    float g = sigmoidf_(acc[qm][qn][mt][nt][r] + bv);
                    float h = bf2f(Hbf[(size_t)(row + r) * DH + col]);
                    Out[(size_t)(row + r) * DH + col] = g * h;
                }
            }
        }
    }
}

// ---------------------------------------------------------------------------
// Scan pass 1: per-chunk aggregates, 4 channels/thread (u16x4 = 8B loads),
// 4 independent recurrence chains per thread for ILP. Block covers all 1024
// channels. grid (NC, BB), block 256.
__global__ __launch_bounds__(256) void scan_chunk_agg(
    const ushort_t* __restrict__ Zarr, const ushort_t* __restrict__ Harr,
    float* __restrict__ Agg, float* __restrict__ Bagg)
{
    const int c4    = threadIdx.x * 4;   // channel base 0..1020
    const int chunk = blockIdx.x;
    const int b     = blockIdx.y;
    const size_t s0 = ((size_t)b * SS + (size_t)chunk * CL) * DH + c4;
    const ushort_t* Zp = Zarr + s0;
    const ushort_t* Hp = Harr + s0;

    float A0 = 1.0f, A1 = 1.0f, A2 = 1.0f, A3 = 1.0f;
    float B0 = 0.0f, B1 = 0.0f, B2 = 0.0f, B3 = 0.0f;
    #pragma unroll 8
    for (int t = 0; t < CL; t++) {
        u16x4 zv = *(const u16x4*)(Zp + (size_t)t * DH);
        u16x4 hv = *(const u16x4*)(Hp + (size_t)t * DH);
        float z0 = bf2f(zv.x), z1 = bf2f(zv.y), z2 = bf2f(zv.z), z3 = bf2f(zv.w);
        float h0 = bf2f(hv.x), h1 = bf2f(hv.y), h2 = bf2f(hv.z), h3 = bf2f(hv.w);
        A0 *= 1.0f - z0;  B0 = (1.0f - z0) * B0 + z0 * h0;
        A1 *= 1.0f - z1;  B1 = (1.0f - z1) * B1 + z1 * h1;
        A2 *= 1.0f - z2;  B2 = (1.0f - z2) * B2 + z2 * h2;
        A3 *= 1.0f - z3;  B3 = (1.0f - z3) * B3 + z3 * h3;
    }
    const size_t idx = ((size_t)(b * NC + chunk)) * DH + c4;
    *(float4*)(Agg  + idx) = make_float4(A0, A1, A2, A3);
    *(float4*)(Bagg + idx) = make_float4(B0, B1, B2, B3);
}

// Scan pass 2: carry across chunks. 4096 threads, 64 sequential L2-hot steps.
__global__ void scan_carry(const float* __restrict__ Agg, const float* __restrict__ Bagg,
                           float* __restrict__ Hinit)
{
    const int i = blockIdx.x * 256 + threadIdx.x;  // 0..4095
    const int b = i >> 10, c = i & 1023;
    float h = 0.0f;
    for (int j = 0; j < NC; j++) {
        const size_t idx = ((size_t)(b * NC + j)) * DH + c;
        Hinit[idx] = h;
        h = Agg[idx] * h + Bagg[idx];
    }
}

// Scan pass 3: re-apply with chunk-initial h (4 ch/thread, vector I/O);
// write h (bf16) in place over Harr.
__global__ __launch_bounds__(256) void scan_apply(
    const ushort_t* __restrict__ Zarr, ushort_t* Harr, const float* __restrict__ Hinit)
{
    const int c4    = threadIdx.x * 4;
    const int chunk = blockIdx.x;
    const int b     = blockIdx.y;
    const size_t s0 = ((size_t)b * SS + (size_t)chunk * CL) * DH + c4;
    const ushort_t* Zp = Zarr + s0;
    ushort_t*       Hp = Harr + s0;

    float4 hi = *(const float4*)(Hinit + ((size_t)(b * NC + chunk)) * DH + c4);
    float h0 = hi.x, h1 = hi.y, h2 = hi.z, h3 = hi.w;
    #pragma unroll 8
    for (int t = 0; t < CL; t++) {
        u16x4 zv = *(const u16x4*)(Zp + (size_t)t * DH);
        u16x4 hv = *(const u16x4*)(Hp + (size_t)t * DH);
        float z0 = bf2f(zv.x), z1 = bf2f(zv.y), z2 = bf2f(zv.z), z3 = bf2f(zv.w);
        float t0 = bf2f(hv.x), t1 = bf2f(hv.y), t2 = bf2f(hv.z), t3 = bf2f(hv.w);
        h0 = (1.0f - z0) * h0 + z0 * t0;
        h1 = (1.0f - z1) * h1 + z1 * t1;
        h2 = (1.0f - z2) * h2 + z2 * t2;
        h3 = (1.0f - z3) * h3 + z3 * t3;
        u16x4 o;
        o.x = f2bf(h0); o.y = f2bf(h1); o.z = f2bf(h2); o.w = f2bf(h3);
        *(u16x4*)(Hp + (size_t)t * DH) = o;
    }
}

// ---------------------------------------------------------------------------
extern "C" void kernel_launch(void* const* d_in, const int* in_sizes, int n_in,
                              void* d_out, int out_size, void* d_ws, size_t ws_size,
                              hipStream_t stream)
{
    const float* x   = (const float*)d_in[0];
    const float* Wzf = (const float*)d_in[1];
    const float* bzf = (const float*)d_in[2];
    const float* Whf = (const float*)d_in[3];
    const float* bhf = (const float*)d_in[4];
    const float* Wzs = (const float*)d_in[5];
    const float* bzs = (const float*)d_in[6];
    const float* Whs = (const float*)d_in[7];
    const float* bhs = (const float*)d_in[8];
    const float* Wg  = (const float*)d_in[9];
    const float* bg  = (const float*)d_in[10];

    const size_t NEED = (size_t)42 << 20;
    if (ws_size < NEED) {
        zero_out_kernel<<<(MM * DH + 255) / 256, 256, 0, stream>>>((float*)d_out, MM * DH);
        return;
    }

    // Workspace layout (42 MiB):
    char* ws = (char*)d_ws;
    ushort_t* WcatT = (ushort_t*)(ws);                                    // 0..4 MiB
    ushort_t* WgT   = (ushort_t*)(ws + ((size_t)4 << 20));                // 4..6 MiB
    float*    bcat  = (float*)   (ws + ((size_t)6 << 20));                // 8 KiB
    float*    Agg   = (float*)   (ws + ((size_t)6 << 20) + (64 << 10));   // 1 MiB
    float*    Bagg  = (float*)   (ws + ((size_t)7 << 20) + (64 << 10));   // 1 MiB
    float*    Hinit = (float*)   (ws + ((size_t)8 << 20) + (64 << 10));   // 1 MiB
    ushort_t* Harr  = (ushort_t*)(ws + ((size_t)10 << 20));               // 10..42 MiB

    // d_out (64 MiB fp32) doubles as bf16 scratch until GEMM2 overwrites it:
    ushort_t* Xb   = (ushort_t*)d_out;              // [0..32 MiB): x in bf16
    ushort_t* Zarr = Xb + (size_t)MM * DH;          // [32..64 MiB): post-sigmoid z

    dim3 blk(256);

    // Fused prep: 5 transposes + x cvt + bias concat
    prep_kernel<<<PREP_NBLK, blk, 0, stream>>>(
        x, Wzf, Wzs, Whf, Whs, Wg, bzf, bzs, bhf, bhs, WcatT, WgT, Xb, bcat);

    // GEMM1: Zarr = sigmoid(Xb@Wz+bz), Harr = Xb@Wh+bh   (M=16384, N=2048, K=1024)
    // 256x256 tiles: grid 64x8 = 512 blocks, 512 threads.
    gemm_kernel<0, PN / 256><<<(MM / 256) * (PN / 256), dim3(512), 0, stream>>>(
        Xb, WcatT, DIN, /*lda=*/DIN, bcat, Zarr, Harr, nullptr, nullptr, nullptr);

    // Chunked scan, 3 deterministic passes (h in place over Harr)
    scan_chunk_agg<<<dim3(NC, BB), blk, 0, stream>>>(Zarr, Harr, Agg, Bagg);
    scan_carry<<<16, 256, 0, stream>>>(Agg, Bagg, Hinit);
    scan_apply<<<dim3(NC, BB), blk, 0, stream>>>(Zarr, Harr, Hinit);

    // GEMM2: out = sigmoid(H @ Wg + bg) * H   (fp32 out, overwrites all of d_out)
    // 256x256 tiles: grid 64x4 = 256 blocks.
    gemm_kernel<1, DH / 256><<<(MM / 256) * (DH / 256), dim3(512), 0, stream>>>(
        Harr, WgT, DIN, /*lda=*/DH, nullptr, nullptr, nullptr, bg, /*Hbf=*/Harr,
        (float*)d_out);
}